// Round 20
// baseline (140.828 us; speedup 1.0000x reference)
//
#include <hip/hip_runtime.h>
#include <hip/hip_bf16.h>
#include <math.h>
#include <stdint.h>

typedef __hip_bfloat16 bf16;
typedef __bf16 bf16x8 __attribute__((ext_vector_type(8)));
typedef float f32x4 __attribute__((ext_vector_type(4)));

#define MFMA16 __builtin_amdgcn_mfma_f32_16x16x32_bf16
#define L2E 1.4426950408889634f

// ---- async global->LDS, 16B per lane; lds dest must be wave-uniform base ----
__device__ __forceinline__ void gll16(const void* gsrc, void* ldst) {
  __builtin_amdgcn_global_load_lds(
      (const __attribute__((address_space(1))) unsigned int*)(uintptr_t)gsrc,
      (__attribute__((address_space(3))) unsigned int*)(uintptr_t)ldst,
      16, 0, 0);
}

// ===== merged prep: pack_adj (1024 blk) + 6x weight transpose (3072 blk)
//       + LayerNorm1 (2048 blk) in ONE launch =====
__global__ __launch_bounds__(256) void prep_k(
    const int* __restrict__ adj, const float* __restrict__ mask,
    unsigned char* __restrict__ adj8,
    const float* __restrict__ s0, const float* __restrict__ s1,
    const float* __restrict__ s2, const float* __restrict__ s3,
    const float* __restrict__ s4, const float* __restrict__ s5,
    bf16* __restrict__ d0, bf16* __restrict__ d1, bf16* __restrict__ d2,
    bf16* __restrict__ d3, bf16* __restrict__ d4, bf16* __restrict__ d5,
    const float* __restrict__ x, const float* __restrict__ gam,
    const float* __restrict__ bet, bf16* __restrict__ ln_out) {
  const int bid = blockIdx.x;
  const int tid = threadIdx.x;
  if (bid < 1024) {
    size_t i0 = ((size_t)bid * 256 + tid) * 16;
    int b = (int)(i0 >> 18);
    int k0 = (int)(i0 & 511);
    const float* mb = mask + b * 512 + k0;
    const int* ap = adj + i0;
    unsigned char o16[16];
#pragma unroll
    for (int j = 0; j < 16; ++j)
      o16[j] = (unsigned char)(ap[j] | (mb[j] == 0.f ? 0x80 : 0));
    *(uint4*)(adj8 + i0) = *(const uint4*)o16;
  } else if (bid < 4096) {
    __shared__ float t[32][33];
    const int wb = bid - 1024;
    const float* W;
    bf16* Wt;
    int K, N, n0, k0;
    if (wb < 1024) {
      int mi = wb >> 8, tt = wb & 255;
      W = (mi == 0) ? s0 : (mi == 1) ? s1 : (mi == 2) ? s2 : s3;
      Wt = (mi == 0) ? d0 : (mi == 1) ? d1 : (mi == 2) ? d2 : d3;
      K = 512; N = 512; n0 = (tt & 15) * 32; k0 = (tt >> 4) * 32;
    } else if (wb < 2048) {
      int tt = wb - 1024;
      W = s4; Wt = d4; K = 512; N = 2048;
      n0 = (tt & 63) * 32; k0 = (tt >> 6) * 32;
    } else {
      int tt = wb - 2048;
      W = s5; Wt = d5; K = 2048; N = 512;
      n0 = (tt & 15) * 32; k0 = (tt >> 4) * 32;
    }
    int tx = tid & 31, ty = tid >> 5;
#pragma unroll
    for (int s = 0; s < 32; s += 8)
      t[ty + s][tx] = W[(size_t)(k0 + ty + s) * N + n0 + tx];
    __syncthreads();
#pragma unroll
    for (int s = 0; s < 32; s += 8)
      Wt[(size_t)(n0 + ty + s) * K + k0 + tx] = (bf16)t[tx][ty + s];
  } else {
    const int lb = bid - 4096;
    int l = tid & 63, w = tid >> 6;
    size_t row = (size_t)lb * 4 + w;
    const float* xr = x + row * 512 + l * 8;
    float4 v0 = *(const float4*)xr;
    float4 v1 = *(const float4*)(xr + 4);
    float s = v0.x + v0.y + v0.z + v0.w + v1.x + v1.y + v1.z + v1.w;
    float q = v0.x * v0.x + v0.y * v0.y + v0.z * v0.z + v0.w * v0.w +
              v1.x * v1.x + v1.y * v1.y + v1.z * v1.z + v1.w * v1.w;
#pragma unroll
    for (int o = 1; o < 64; o <<= 1) { s += __shfl_xor(s, o); q += __shfl_xor(q, o); }
    float mean = s * (1.0f / 512.0f);
    float var = q * (1.0f / 512.0f) - mean * mean;
    float rstd = rsqrtf(var + 1e-5f);
    const float* gr = gam + l * 8;
    const float* br = bet + l * 8;
    float4 ga = *(const float4*)gr, gb = *(const float4*)(gr + 4);
    float4 ba = *(const float4*)br, bb = *(const float4*)(br + 4);
    bf16 t8[8];
    t8[0] = (bf16)((v0.x - mean) * rstd * ga.x + ba.x);
    t8[1] = (bf16)((v0.y - mean) * rstd * ga.y + ba.y);
    t8[2] = (bf16)((v0.z - mean) * rstd * ga.z + ba.z);
    t8[3] = (bf16)((v0.w - mean) * rstd * ga.w + ba.w);
    t8[4] = (bf16)((v1.x - mean) * rstd * gb.x + bb.x);
    t8[5] = (bf16)((v1.y - mean) * rstd * gb.y + bb.y);
    t8[6] = (bf16)((v1.z - mean) * rstd * gb.z + bb.z);
    t8[7] = (bf16)((v1.w - mean) * rstd * gb.w + bb.w);
    *(uint4*)(ln_out + row * 512 + l * 8) = *(const uint4*)t8;
  }
}

// =====================  LayerNorm2: bf16 in -> bf16 out, one row per wave ======
__global__ __launch_bounds__(256) void ln_b_k(const bf16* __restrict__ x,
                                              const float* __restrict__ gam,
                                              const float* __restrict__ bet,
                                              bf16* __restrict__ out) {
  int l = threadIdx.x & 63, w = threadIdx.x >> 6;
  size_t row = (size_t)blockIdx.x * 4 + w;
  uint4 raw = *(const uint4*)(x + row * 512 + l * 8);
  const bf16* pv = (const bf16*)&raw;
  float v[8];
#pragma unroll
  for (int j = 0; j < 8; ++j) v[j] = (float)pv[j];
  float s = 0.f, q = 0.f;
#pragma unroll
  for (int j = 0; j < 8; ++j) { s += v[j]; q += v[j] * v[j]; }
#pragma unroll
  for (int o = 1; o < 64; o <<= 1) { s += __shfl_xor(s, o); q += __shfl_xor(q, o); }
  float mean = s * (1.0f / 512.0f);
  float var = q * (1.0f / 512.0f) - mean * mean;
  float rstd = rsqrtf(var + 1e-5f);
  const float* gr = gam + l * 8;
  const float* br = bet + l * 8;
  float4 ga = *(const float4*)gr, gb = *(const float4*)(gr + 4);
  float4 ba = *(const float4*)br, bb = *(const float4*)(br + 4);
  float gg[8] = {ga.x, ga.y, ga.z, ga.w, gb.x, gb.y, gb.z, gb.w};
  float bb8[8] = {ba.x, ba.y, ba.z, ba.w, bb.x, bb.y, bb.z, bb.w};
  bf16 t8[8];
#pragma unroll
  for (int j = 0; j < 8; ++j) t8[j] = (bf16)((v[j] - mean) * rstd * gg[j] + bb8[j]);
  *(uint4*)(out + row * 512 + l * 8) = *(const uint4*)t8;
}

// =====================  GEMM: A[M][K] bf16 x Bt[N][K] bf16, tile BMxBN =========
// Double-buffered LDS, issue-early staging, one barrier per K-step.
// 256x64 for QKV/FF1 (80KB LDS, 2 blocks/CU, 320 B staged per MFMA);
// 64x64 for Wo/FF2 (N=512 keeps grid at 1024 blocks).
template <int MODE, int BM, int BN>
__global__ __launch_bounds__(256) void gemm_bt(
    const bf16* __restrict__ A, const bf16* __restrict__ Bt, int M, int N, int K,
    const float* __restrict__ b0, const float* __restrict__ b1p,
    const float* __restrict__ b2p, const float* __restrict__ resid,
    const float* __restrict__ mrow, float* __restrict__ outF,
    bf16* __restrict__ outH, bf16* __restrict__ outV,
    const bf16* __restrict__ residH) {
  constexpr int RA = BM / 32, RB = BN / 32;
  __shared__ __align__(16) bf16 Asw[2][BM * 64];
  __shared__ __align__(16) bf16 Bsw[2][BN * 64];
  const int tid = threadIdx.x;
  const int l = tid & 63, w = tid >> 6;
  const int g = l >> 4, ln = l & 15;
  const int wm = w >> 1, wn = w & 1;
  const int m0 = blockIdx.x * BM, n0 = blockIdx.y * BN;

  f32x4 acc[RA][RB];
  f32x4 zero = {0.f, 0.f, 0.f, 0.f};
#pragma unroll
  for (int i = 0; i < RA; ++i)
#pragma unroll
    for (int j = 0; j < RB; ++j) acc[i][j] = zero;

  const bf16* aSrc[RA];
  const bf16* bSrc[RB];
#pragma unroll
  for (int rr = 0; rr < RA; ++rr) {
    int m = w * (BM / 4) + rr * 8 + (l >> 3);
    int gs = (l & 7) ^ (m & 7);
    aSrc[rr] = A + (size_t)(m0 + m) * K + gs * 8;
  }
#pragma unroll
  for (int rr = 0; rr < RB; ++rr) {
    int n = w * (BN / 4) + rr * 8 + (l >> 3);
    int gs = (l & 7) ^ (n & 7);
    bSrc[rr] = Bt + (size_t)(n0 + n) * K + gs * 8;
  }

  const int NT = K >> 6;
#pragma unroll
  for (int rr = 0; rr < RA; ++rr) gll16(aSrc[rr], &Asw[0][w * (BM * 16) + rr * 512]);
#pragma unroll
  for (int rr = 0; rr < RB; ++rr) gll16(bSrc[rr], &Bsw[0][w * (BN * 16) + rr * 512]);
  __syncthreads();

  for (int ti = 0; ti < NT; ++ti) {
    const int cur = ti & 1, nxt = cur ^ 1;
    if (ti + 1 < NT) {
      const int kt = (ti + 1) << 6;
#pragma unroll
      for (int rr = 0; rr < RA; ++rr)
        gll16(aSrc[rr] + kt, &Asw[nxt][w * (BM * 16) + rr * 512]);
#pragma unroll
      for (int rr = 0; rr < RB; ++rr)
        gll16(bSrc[rr] + kt, &Bsw[nxt][w * (BN * 16) + rr * 512]);
    }
#pragma unroll
    for (int kk = 0; kk < 2; ++kk) {
      bf16x8 af[RA], bfr[RB];
#pragma unroll
      for (int mt = 0; mt < RA; ++mt) {
        int m = wm * (BM / 2) + mt * 16 + ln;
        af[mt] = *(const bf16x8*)&Asw[cur][m * 64 + (((kk * 4 + g) ^ (m & 7)) * 8)];
      }
#pragma unroll
      for (int nt = 0; nt < RB; ++nt) {
        int n = wn * (BN / 2) + nt * 16 + ln;
        bfr[nt] = *(const bf16x8*)&Bsw[cur][n * 64 + (((kk * 4 + g) ^ (n & 7)) * 8)];
      }
#pragma unroll
      for (int mt = 0; mt < RA; ++mt)
#pragma unroll
        for (int nt = 0; nt < RB; ++nt)
          acc[mt][nt] = MFMA16(af[mt], bfr[nt], acc[mt][nt], 0, 0, 0);
    }
    __syncthreads();
  }

  if (MODE == 0 && blockIdx.y >= 16) {
    // ---- V third (BM x 64, one head per block): transpose through LDS
    // (reuse Asw: 64 cols x BM k = BM*128 B), (BM/4)-granule XOR swizzle,
    // then 16B/lane coalesced stores over k ----
    constexpr int GMASK = BM / 4 - 1;       // granule-index mask per column
    constexpr int BPB = 512 / BM;           // blocks per batch along M
    bf16* lt = &Asw[0][0];
    const int by = blockIdx.y;
#pragma unroll
    for (int nt = 0; nt < RB; ++nt) {
      const int col = wn * (BN / 2) + nt * 16 + ln;  // local d 0..63
      const float bias = b2p[(by - 16) * 64 + col];
#pragma unroll
      for (int mt = 0; mt < RA; ++mt) {
        const int gr_w = wm * (BM / 8) + mt * 4 + g;  // k-granule 0..BM/4-1
        bf16 t4[4];
#pragma unroll
        for (int r = 0; r < 4; ++r) t4[r] = (bf16)(acc[mt][nt][r] + bias);
        *(uint2*)&lt[col * BM + ((gr_w ^ (col & GMASK)) << 2)] = *(const uint2*)t4;
      }
    }
    __syncthreads();
    const int bq = blockIdx.x / BPB;
    const int q0 = (blockIdx.x % BPB) * BM;
#pragma unroll
    for (int j = 0; j < BM / 32; ++j) {
      const int flat = j * 256 + tid;        // 0 .. 64*BM/8-1 uint4 slots
      const int col = flat / (BM / 8), seg = flat % (BM / 8);
      const int sg0 = (2 * seg) ^ (col & GMASK);
      const int sg1 = (2 * seg + 1) ^ (col & GMASK);
      uint2 u0 = *(const uint2*)&lt[col * BM + (sg0 << 2)];
      uint2 u1 = *(const uint2*)&lt[col * BM + (sg1 << 2)];
      uint4 u;
      u.x = u0.x; u.y = u0.y; u.z = u1.x; u.w = u1.y;
      *(uint4*)&outV[(((size_t)(bq * 8 + (by - 16))) * 64 + col) * 512 + q0 + seg * 8] = u;
    }
    return;
  }

#pragma unroll
  for (int mt = 0; mt < RA; ++mt) {
#pragma unroll
    for (int nt = 0; nt < RB; ++nt) {
      if (MODE == 0) {
        const int gn = n0 + wn * (BN / 2) + nt * 16 + ln;
        const int which = gn >> 9;  // 0=Q, 1=K (V handled above)
        const int dm = gn & 511;
        const int hh = dm >> 6, hd = dm & 63;
        const float bias = (which == 0) ? b0[dm] : b1p[dm];
        const int gm0 = m0 + wm * (BM / 2) + mt * 16 + g * 4;
        const int bq = gm0 >> 9, qq0 = gm0 & 511;
#pragma unroll
        for (int r = 0; r < 4; ++r) {
          float v = acc[mt][nt][r] + bias;
          if (which == 0) v *= 0.125f * L2E;  // fold 1/sqrt(64) and log2(e) into Q
          outH[(size_t)which * 4194304 + (((size_t)(bq * 8 + hh)) * 512 + qq0 + r) * 64 + hd] =
              (bf16)v;
        }
      } else {
#pragma unroll
        for (int r = 0; r < 4; ++r) {
          int gm = m0 + wm * (BM / 2) + mt * 16 + g * 4 + r;
          int gn = n0 + wn * (BN / 2) + nt * 16 + ln;
          float v = acc[mt][nt][r];
          if (MODE == 1) {
            v += b0[gn] + resid[(size_t)gm * 512 + gn];
            outH[(size_t)gm * 512 + gn] = (bf16)v;  // xmid in bf16
          } else if (MODE == 2) {
            v += b0[gn];
            // tanh-form GELU: v * sigmoid(2*0.7978845608*(v + 0.044715 v^3))
            float t = 2.302587f * (v + 0.044715f * v * v * v);  // 2*L2E*0.79788
            float e = __builtin_amdgcn_exp2f(t);
            v = v * e / (1.0f + e);
            outH[(size_t)gm * 2048 + gn] = (bf16)v;
          } else {
            v += b0[gn] + (float)residH[(size_t)gm * 512 + gn];
            v *= mrow[gm];
            outF[(size_t)gm * 512 + gn] = v;
          }
        }
      }
    }
  }
}

// =====================  fused attention (flash, no-max online softmax) =========
// 256 thr / 4 waves / 40KB LDS / 4 blocks/CU. K AND V^T staged via gll16.
// adj8 prefetched one tile ahead; edge bias via register cmp-select chain.
// rowlive applied only at final normalize. s_setprio on MFMA clusters.
// XCD-locality grid: blockIdx.x = h*16 + b.
__global__ __launch_bounds__(256, 4) void attn_k(
    const bf16* __restrict__ Qg, const bf16* __restrict__ Kg,
    const bf16* __restrict__ Vtg, const unsigned char* __restrict__ adj8,
    const float* __restrict__ mask, const float* __restrict__ ebias,
    bf16* __restrict__ out) {
  __shared__ __align__(16) bf16 Ksw[2][64 * 64];  // [k][d], granule ^= (k&7) via src
  __shared__ __align__(16) bf16 Vt[2][64 * 64];   // [d][k], granule ^= (d&7) via src
  __shared__ __align__(16) bf16 Pb[4][16 * 64];   // per-wave P, granule ^= (q&7)
  const int tid = threadIdx.x;
  const int l = tid & 63, w = tid >> 6, g = l >> 4, ln = l & 15;
  const int bhx = blockIdx.x;
  const int b = bhx & 15, h = bhx >> 4;
  const int bh = b * 8 + h;
  const int qt = blockIdx.y;
  const bf16* kb = Kg + (size_t)bh * 512 * 64;
  const bf16* vtb = Vtg + (size_t)bh * 64 * 512;

  int ksrc_off[2], vtsrc_off[2];
#pragma unroll
  for (int rr = 0; rr < 2; ++rr) {
    int m = w * 16 + rr * 8 + (l >> 3);
    int gs = (l & 7) ^ (l >> 3);  // (l&7)^(m&7), m&7 == l>>3
    ksrc_off[rr] = m * 64 + gs * 8;    // K row stride 64
    vtsrc_off[rr] = m * 512 + gs * 8;  // V^T row (d) stride 512
  }

  const int qrow = qt * 64 + w * 16 + ln;
  const bf16* qp = Qg + ((size_t)bh * 512 + qrow) * 64;
  bf16x8 qf0 = *(const bf16x8*)(qp + g * 8);
  bf16x8 qf1 = *(const bf16x8*)(qp + 32 + g * 8);

  const bool rowlive = mask[b * 512 + qrow] != 0.f;
  float e0 = ebias[0 * 8 + h] * L2E, e1 = ebias[1 * 8 + h] * L2E;
  float e2 = ebias[2 * 8 + h] * L2E, e3 = ebias[3 * 8 + h] * L2E;
  float e4 = ebias[4 * 8 + h] * L2E;
  const unsigned char* adjq = adj8 + ((size_t)b * 512 + qrow) * 512;

  f32x4 zero = {0.f, 0.f, 0.f, 0.f};
  f32x4 o[4];
#pragma unroll
  for (int dt = 0; dt < 4; ++dt) o[dt] = zero;
  float rsum = 0.f;
  bf16* pw = &Pb[w][0];

  // ---- prologue: stage tile 0 (K + V^T via gll16); prefetch adj bytes ----
#pragma unroll
  for (int rr = 0; rr < 2; ++rr) {
    gll16(kb + ksrc_off[rr], &Ksw[0][w * 1024 + rr * 512]);
    gll16(vtb + vtsrc_off[rr], &Vt[0][w * 1024 + rr * 512]);
  }
  uchar4 c4[4];
#pragma unroll
  for (int t4 = 0; t4 < 4; ++t4) c4[t4] = *(const uchar4*)(adjq + t4 * 16 + g * 4);
  __syncthreads();

  for (int t = 0; t < 8; ++t) {
    const int cur = t & 1, nxt = cur ^ 1;
    uchar4 n4[4];
    if (t < 7) {
      const bf16* kbt = kb + (t + 1) * 4096;
      const bf16* vbt = vtb + (t + 1) * 64;
#pragma unroll
      for (int rr = 0; rr < 2; ++rr) {
        gll16(kbt + ksrc_off[rr], &Ksw[nxt][w * 1024 + rr * 512]);
        gll16(vbt + vtsrc_off[rr], &Vt[nxt][w * 1024 + rr * 512]);
      }
#pragma unroll
      for (int t4 = 0; t4 < 4; ++t4)
        n4[t4] = *(const uchar4*)(adjq + (t + 1) * 64 + t4 * 16 + g * 4);
    }

    // ---- QK^T on current tile ----
    f32x4 s[4];
    __builtin_amdgcn_s_setprio(1);
#pragma unroll
    for (int t4 = 0; t4 < 4; ++t4) {
      int kr = t4 * 16 + ln;
      s[t4] = zero;
      bf16x8 a0 = *(const bf16x8*)&Ksw[cur][kr * 64 + ((g ^ (ln & 7)) * 8)];
      s[t4] = MFMA16(a0, qf0, s[t4], 0, 0, 0);
      bf16x8 a1 = *(const bf16x8*)&Ksw[cur][kr * 64 + (((4 + g) ^ (ln & 7)) * 8)];
      s[t4] = MFMA16(a1, qf1, s[t4], 0, 0, 0);
    }
    __builtin_amdgcn_s_setprio(0);

    // ---- edge/mask byte (register select) + exp2 (no max), rsum, stage P ----
#pragma unroll
    for (int t4 = 0; t4 < 4; ++t4) {
      unsigned char cv[4] = {c4[t4].x, c4[t4].y, c4[t4].z, c4[t4].w};
      bf16 hb[4];
#pragma unroll
      for (int r = 0; r < 4; ++r) {
        int a = cv[r] & 7;
        float eb = (a == 0) ? e0 : (a == 1) ? e1 : (a == 2) ? e2 : (a == 3) ? e3 : e4;
        float p = (cv[r] & 0x80) ? 0.f : __builtin_amdgcn_exp2f(s[t4][r] + eb);
        rsum += p;
        hb[r] = (bf16)p;
      }
      int sub = t4 * 2 + (g >> 1);
      *(uint2*)&pw[ln * 64 + ((sub ^ (ln & 7)) * 8) + (g & 1) * 4] = *(const uint2*)hb;
    }

    // ---- PV: O += P * V^T (unnormalized) ----
    __builtin_amdgcn_s_setprio(1);
#pragma unroll
    for (int ks = 0; ks < 2; ++ks) {
      bf16x8 pa = *(const bf16x8*)&pw[ln * 64 + (((ks * 4 + g) ^ (ln & 7)) * 8)];
#pragma unroll
      for (int dt = 0; dt < 4; ++dt) {
        int d = dt * 16 + ln;
        bf16x8 vvv = *(const bf16x8*)&Vt[cur][d * 64 + (((ks * 4 + g) ^ (d & 7)) * 8)];
        o[dt] = MFMA16(pa, vvv, o[dt], 0, 0, 0);
      }
    }
    __builtin_amdgcn_s_setprio(0);
    __syncthreads();
    if (t < 7) {
#pragma unroll
      for (int t4 = 0; t4 < 4; ++t4) c4[t4] = n4[t4];
    }
  }

  // ---- normalize and write (rowlive applied here: dead q-row -> 0) ----
  rsum += __shfl_xor(rsum, 16);
  rsum += __shfl_xor(rsum, 32);
  float inv = (rowlive && rsum > 0.f) ? 1.f / rsum : 0.f;
  const int qbase = qt * 64 + w * 16;
#pragma unroll
  for (int r = 0; r < 4; ++r) {
    float invr = __shfl(inv, g * 4 + r);
#pragma unroll
    for (int dt = 0; dt < 4; ++dt) {
      int q = qbase + g * 4 + r;
      out[((size_t)b * 512 + q) * 512 + h * 64 + dt * 16 + ln] = (bf16)(o[dt][r] * invr);
    }
  }
}

// ============================================================================
extern "C" void kernel_launch(void* const* d_in, const int* in_sizes, int n_in,
                              void* d_out, int out_size, void* d_ws, size_t ws_size,
                              hipStream_t stream) {
  const float* x = (const float*)d_in[0];
  const int* adj = (const int*)d_in[1];
  const float* mask = (const float*)d_in[2];
  const float* Wq = (const float*)d_in[3];
  const float* bq = (const float*)d_in[4];
  const float* Wk = (const float*)d_in[5];
  const float* bk = (const float*)d_in[6];
  const float* Wv = (const float*)d_in[7];
  const float* bv = (const float*)d_in[8];
  const float* Wo = (const float*)d_in[9];
  const float* bo = (const float*)d_in[10];
  const float* ebias = (const float*)d_in[11];
  const float* W1 = (const float*)d_in[12];
  const float* b1 = (const float*)d_in[13];
  const float* W2 = (const float*)d_in[14];
  const float* b2 = (const float*)d_in[15];
  const float* g1 = (const float*)d_in[16];
  const float* be1 = (const float*)d_in[17];
  const float* g2 = (const float*)d_in[18];
  const float* be2 = (const float*)d_in[19];
  float* outp = (float*)d_out;

  char* ws = (char*)d_ws;
  size_t off = 0;
  auto alloc = [&](size_t bytes) {
    void* p = ws + off;
    off += (bytes + 255) & ~(size_t)255;
    return p;
  };
  const size_t QSZ = 4194304;  // B*H*512*64
  bf16* h1 = (bf16*)alloc(8192UL * 512 * 2);
  bf16* wqkv = (bf16*)alloc(1536UL * 512 * 2);
  bf16* wo_t = (bf16*)alloc(512UL * 512 * 2);
  bf16* w1_t = (bf16*)alloc(2048UL * 512 * 2);
  bf16* w2_t = (bf16*)alloc(512UL * 2048 * 2);
  bf16* qkv = (bf16*)alloc(2UL * QSZ * 2);          // Q, K
  bf16* vt = (bf16*)alloc(QSZ * 2);                 // V^T [bh][d][k]
  bf16* aout = (bf16*)alloc(8192UL * 512 * 2);
  bf16* xmid = (bf16*)alloc(8192UL * 512 * 2);      // residual stream in bf16
  bf16* h2 = (bf16*)alloc(8192UL * 512 * 2);
  bf16* a1 = (bf16*)alloc(8192UL * 2048 * 2);
  unsigned char* adj8 = (unsigned char*)alloc(4194304UL);
  if (off > ws_size) return;  // workspace too small: fail cleanly

  prep_k<<<6144, 256, 0, stream>>>(adj, mask, adj8, Wq, Wk, Wv, Wo, W1, W2, wqkv,
                                   wqkv + 512 * 512, wqkv + 1024 * 512, wo_t, w1_t,
                                   w2_t, x, g1, be1, h1);
  gemm_bt<0, 256, 64><<<dim3(32, 24), 256, 0, stream>>>(
      h1, wqkv, 8192, 1536, 512, bq, bk, bv, nullptr, nullptr, nullptr, qkv, vt,
      nullptr);
  attn_k<<<dim3(128, 8), 256, 0, stream>>>(qkv, qkv + QSZ, vt, adj8, mask, ebias, aout);
  gemm_bt<1, 64, 64><<<dim3(128, 8), 256, 0, stream>>>(
      aout, wo_t, 8192, 512, 512, bo, nullptr, nullptr, x, nullptr, nullptr, xmid,
      nullptr, nullptr);
  ln_b_k<<<2048, 256, 0, stream>>>(xmid, g2, be2, h2);
  gemm_bt<2, 256, 64><<<dim3(32, 32), 256, 0, stream>>>(
      h2, w1_t, 8192, 2048, 512, b1, nullptr, nullptr, nullptr, nullptr, nullptr, a1,
      nullptr, nullptr);
  gemm_bt<3, 64, 64><<<dim3(128, 8), 256, 0, stream>>>(
      a1, w2_t, 8192, 512, 2048, b2, nullptr, nullptr, nullptr, mask, outp, nullptr,
      nullptr, xmid);
}

// Round 21
// 137.758 us; speedup vs baseline: 1.0223x; 1.0223x over previous
//
#include <hip/hip_runtime.h>
#include <hip/hip_bf16.h>
#include <math.h>
#include <stdint.h>

typedef __hip_bfloat16 bf16;
typedef __bf16 bf16x8 __attribute__((ext_vector_type(8)));
typedef float f32x4 __attribute__((ext_vector_type(4)));

#define MFMA16 __builtin_amdgcn_mfma_f32_16x16x32_bf16
#define L2E 1.4426950408889634f

// ---- async global->LDS, 16B per lane; lds dest must be wave-uniform base ----
__device__ __forceinline__ void gll16(const void* gsrc, void* ldst) {
  __builtin_amdgcn_global_load_lds(
      (const __attribute__((address_space(1))) unsigned int*)(uintptr_t)gsrc,
      (__attribute__((address_space(3))) unsigned int*)(uintptr_t)ldst,
      16, 0, 0);
}

// ===== merged prep: pack_adj (1024 blk) + 6x weight transpose (3072 blk)
//       + LayerNorm1 (2048 blk) in ONE launch =====
__global__ __launch_bounds__(256) void prep_k(
    const int* __restrict__ adj, const float* __restrict__ mask,
    unsigned char* __restrict__ adj8,
    const float* __restrict__ s0, const float* __restrict__ s1,
    const float* __restrict__ s2, const float* __restrict__ s3,
    const float* __restrict__ s4, const float* __restrict__ s5,
    bf16* __restrict__ d0, bf16* __restrict__ d1, bf16* __restrict__ d2,
    bf16* __restrict__ d3, bf16* __restrict__ d4, bf16* __restrict__ d5,
    const float* __restrict__ x, const float* __restrict__ gam,
    const float* __restrict__ bet, bf16* __restrict__ ln_out) {
  const int bid = blockIdx.x;
  const int tid = threadIdx.x;
  if (bid < 1024) {
    size_t i0 = ((size_t)bid * 256 + tid) * 16;
    int b = (int)(i0 >> 18);
    int k0 = (int)(i0 & 511);
    const float* mb = mask + b * 512 + k0;
    const int* ap = adj + i0;
    unsigned char o16[16];
#pragma unroll
    for (int j = 0; j < 16; ++j)
      o16[j] = (unsigned char)(ap[j] | (mb[j] == 0.f ? 0x80 : 0));
    *(uint4*)(adj8 + i0) = *(const uint4*)o16;
  } else if (bid < 4096) {
    __shared__ float t[32][33];
    const int wb = bid - 1024;
    const float* W;
    bf16* Wt;
    int K, N, n0, k0;
    if (wb < 1024) {
      int mi = wb >> 8, tt = wb & 255;
      W = (mi == 0) ? s0 : (mi == 1) ? s1 : (mi == 2) ? s2 : s3;
      Wt = (mi == 0) ? d0 : (mi == 1) ? d1 : (mi == 2) ? d2 : d3;
      K = 512; N = 512; n0 = (tt & 15) * 32; k0 = (tt >> 4) * 32;
    } else if (wb < 2048) {
      int tt = wb - 1024;
      W = s4; Wt = d4; K = 512; N = 2048;
      n0 = (tt & 63) * 32; k0 = (tt >> 6) * 32;
    } else {
      int tt = wb - 2048;
      W = s5; Wt = d5; K = 2048; N = 512;
      n0 = (tt & 15) * 32; k0 = (tt >> 4) * 32;
    }
    int tx = tid & 31, ty = tid >> 5;
#pragma unroll
    for (int s = 0; s < 32; s += 8)
      t[ty + s][tx] = W[(size_t)(k0 + ty + s) * N + n0 + tx];
    __syncthreads();
#pragma unroll
    for (int s = 0; s < 32; s += 8)
      Wt[(size_t)(n0 + ty + s) * K + k0 + tx] = (bf16)t[tx][ty + s];
  } else {
    const int lb = bid - 4096;
    int l = tid & 63, w = tid >> 6;
    size_t row = (size_t)lb * 4 + w;
    const float* xr = x + row * 512 + l * 8;
    float4 v0 = *(const float4*)xr;
    float4 v1 = *(const float4*)(xr + 4);
    float s = v0.x + v0.y + v0.z + v0.w + v1.x + v1.y + v1.z + v1.w;
    float q = v0.x * v0.x + v0.y * v0.y + v0.z * v0.z + v0.w * v0.w +
              v1.x * v1.x + v1.y * v1.y + v1.z * v1.z + v1.w * v1.w;
#pragma unroll
    for (int o = 1; o < 64; o <<= 1) { s += __shfl_xor(s, o); q += __shfl_xor(q, o); }
    float mean = s * (1.0f / 512.0f);
    float var = q * (1.0f / 512.0f) - mean * mean;
    float rstd = rsqrtf(var + 1e-5f);
    const float* gr = gam + l * 8;
    const float* br = bet + l * 8;
    float4 ga = *(const float4*)gr, gb = *(const float4*)(gr + 4);
    float4 ba = *(const float4*)br, bb = *(const float4*)(br + 4);
    bf16 t8[8];
    t8[0] = (bf16)((v0.x - mean) * rstd * ga.x + ba.x);
    t8[1] = (bf16)((v0.y - mean) * rstd * ga.y + ba.y);
    t8[2] = (bf16)((v0.z - mean) * rstd * ga.z + ba.z);
    t8[3] = (bf16)((v0.w - mean) * rstd * ga.w + ba.w);
    t8[4] = (bf16)((v1.x - mean) * rstd * gb.x + bb.x);
    t8[5] = (bf16)((v1.y - mean) * rstd * gb.y + bb.y);
    t8[6] = (bf16)((v1.z - mean) * rstd * gb.z + bb.z);
    t8[7] = (bf16)((v1.w - mean) * rstd * gb.w + bb.w);
    *(uint4*)(ln_out + row * 512 + l * 8) = *(const uint4*)t8;
  }
}

// =====================  LayerNorm2: bf16 in -> bf16 out, one row per wave ======
__global__ __launch_bounds__(256) void ln_b_k(const bf16* __restrict__ x,
                                              const float* __restrict__ gam,
                                              const float* __restrict__ bet,
                                              bf16* __restrict__ out) {
  int l = threadIdx.x & 63, w = threadIdx.x >> 6;
  size_t row = (size_t)blockIdx.x * 4 + w;
  uint4 raw = *(const uint4*)(x + row * 512 + l * 8);
  const bf16* pv = (const bf16*)&raw;
  float v[8];
#pragma unroll
  for (int j = 0; j < 8; ++j) v[j] = (float)pv[j];
  float s = 0.f, q = 0.f;
#pragma unroll
  for (int j = 0; j < 8; ++j) { s += v[j]; q += v[j] * v[j]; }
#pragma unroll
  for (int o = 1; o < 64; o <<= 1) { s += __shfl_xor(s, o); q += __shfl_xor(q, o); }
  float mean = s * (1.0f / 512.0f);
  float var = q * (1.0f / 512.0f) - mean * mean;
  float rstd = rsqrtf(var + 1e-5f);
  const float* gr = gam + l * 8;
  const float* br = bet + l * 8;
  float4 ga = *(const float4*)gr, gb = *(const float4*)(gr + 4);
  float4 ba = *(const float4*)br, bb = *(const float4*)(br + 4);
  float gg[8] = {ga.x, ga.y, ga.z, ga.w, gb.x, gb.y, gb.z, gb.w};
  float bb8[8] = {ba.x, ba.y, ba.z, ba.w, bb.x, bb.y, bb.z, bb.w};
  bf16 t8[8];
#pragma unroll
  for (int j = 0; j < 8; ++j) t8[j] = (bf16)((v[j] - mean) * rstd * gg[j] + bb8[j]);
  *(uint4*)(out + row * 512 + l * 8) = *(const uint4*)t8;
}

// =====================  GEMM: A[M][K] bf16 x Bt[N][K] bf16, tile BMxBN =========
// Double-buffered LDS, issue-early staging, one barrier per K-step.
// 128x64 for QKV/FF1 (48KB LDS -> 3 blocks/CU: measured optimum; 256x64 at
// 2 blocks/CU regressed +3us in R20), 64x64 for Wo/FF2.
template <int MODE, int BM, int BN>
__global__ __launch_bounds__(256) void gemm_bt(
    const bf16* __restrict__ A, const bf16* __restrict__ Bt, int M, int N, int K,
    const float* __restrict__ b0, const float* __restrict__ b1p,
    const float* __restrict__ b2p, const float* __restrict__ resid,
    const float* __restrict__ mrow, float* __restrict__ outF,
    bf16* __restrict__ outH, bf16* __restrict__ outV,
    const bf16* __restrict__ residH) {
  constexpr int RA = BM / 32, RB = BN / 32;
  __shared__ __align__(16) bf16 Asw[2][BM * 64];
  __shared__ __align__(16) bf16 Bsw[2][BN * 64];
  const int tid = threadIdx.x;
  const int l = tid & 63, w = tid >> 6;
  const int g = l >> 4, ln = l & 15;
  const int wm = w >> 1, wn = w & 1;
  const int m0 = blockIdx.x * BM, n0 = blockIdx.y * BN;

  f32x4 acc[RA][RB];
  f32x4 zero = {0.f, 0.f, 0.f, 0.f};
#pragma unroll
  for (int i = 0; i < RA; ++i)
#pragma unroll
    for (int j = 0; j < RB; ++j) acc[i][j] = zero;

  const bf16* aSrc[RA];
  const bf16* bSrc[RB];
#pragma unroll
  for (int rr = 0; rr < RA; ++rr) {
    int m = w * (BM / 4) + rr * 8 + (l >> 3);
    int gs = (l & 7) ^ (m & 7);
    aSrc[rr] = A + (size_t)(m0 + m) * K + gs * 8;
  }
#pragma unroll
  for (int rr = 0; rr < RB; ++rr) {
    int n = w * (BN / 4) + rr * 8 + (l >> 3);
    int gs = (l & 7) ^ (n & 7);
    bSrc[rr] = Bt + (size_t)(n0 + n) * K + gs * 8;
  }

  const int NT = K >> 6;
#pragma unroll
  for (int rr = 0; rr < RA; ++rr) gll16(aSrc[rr], &Asw[0][w * (BM * 16) + rr * 512]);
#pragma unroll
  for (int rr = 0; rr < RB; ++rr) gll16(bSrc[rr], &Bsw[0][w * (BN * 16) + rr * 512]);
  __syncthreads();

  for (int ti = 0; ti < NT; ++ti) {
    const int cur = ti & 1, nxt = cur ^ 1;
    if (ti + 1 < NT) {
      const int kt = (ti + 1) << 6;
#pragma unroll
      for (int rr = 0; rr < RA; ++rr)
        gll16(aSrc[rr] + kt, &Asw[nxt][w * (BM * 16) + rr * 512]);
#pragma unroll
      for (int rr = 0; rr < RB; ++rr)
        gll16(bSrc[rr] + kt, &Bsw[nxt][w * (BN * 16) + rr * 512]);
    }
#pragma unroll
    for (int kk = 0; kk < 2; ++kk) {
      bf16x8 af[RA], bfr[RB];
#pragma unroll
      for (int mt = 0; mt < RA; ++mt) {
        int m = wm * (BM / 2) + mt * 16 + ln;
        af[mt] = *(const bf16x8*)&Asw[cur][m * 64 + (((kk * 4 + g) ^ (m & 7)) * 8)];
      }
#pragma unroll
      for (int nt = 0; nt < RB; ++nt) {
        int n = wn * (BN / 2) + nt * 16 + ln;
        bfr[nt] = *(const bf16x8*)&Bsw[cur][n * 64 + (((kk * 4 + g) ^ (n & 7)) * 8)];
      }
#pragma unroll
      for (int mt = 0; mt < RA; ++mt)
#pragma unroll
        for (int nt = 0; nt < RB; ++nt)
          acc[mt][nt] = MFMA16(af[mt], bfr[nt], acc[mt][nt], 0, 0, 0);
    }
    __syncthreads();
  }

  if (MODE == 0 && blockIdx.y >= 16) {
    // ---- V third (128 x 64, one head per block): transpose through LDS,
    // 32-granule XOR swizzle, then 16B/lane coalesced stores over k ----
    bf16* lt = &Asw[0][0];
    const int by = blockIdx.y;
#pragma unroll
    for (int nt = 0; nt < RB; ++nt) {
      const int col = wn * (BN / 2) + nt * 16 + ln;  // local d 0..63
      const float bias = b2p[(by - 16) * 64 + col];
#pragma unroll
      for (int mt = 0; mt < RA; ++mt) {
        const int gr_w = wm * 16 + mt * 4 + g;  // k-granule 0..31 (4 rows each)
        bf16 t4[4];
#pragma unroll
        for (int r = 0; r < 4; ++r) t4[r] = (bf16)(acc[mt][nt][r] + bias);
        *(uint2*)&lt[col * 128 + ((gr_w ^ (col & 31)) << 2)] = *(const uint2*)t4;
      }
    }
    __syncthreads();
    const int bq = blockIdx.x >> 2;
    const int q0 = (blockIdx.x & 3) * 128;
#pragma unroll
    for (int j = 0; j < 4; ++j) {
      const int flat = j * 256 + tid;  // 0..1023 uint4 slots
      const int col = flat >> 4, seg = flat & 15;
      const int sg0 = (2 * seg) ^ (col & 31);
      const int sg1 = (2 * seg + 1) ^ (col & 31);
      uint2 u0 = *(const uint2*)&lt[col * 128 + (sg0 << 2)];
      uint2 u1 = *(const uint2*)&lt[col * 128 + (sg1 << 2)];
      uint4 u;
      u.x = u0.x; u.y = u0.y; u.z = u1.x; u.w = u1.y;
      *(uint4*)&outV[(((size_t)(bq * 8 + (by - 16))) * 64 + col) * 512 + q0 + seg * 8] = u;
    }
    return;
  }

#pragma unroll
  for (int mt = 0; mt < RA; ++mt) {
#pragma unroll
    for (int nt = 0; nt < RB; ++nt) {
      if (MODE == 0) {
        const int gn = n0 + wn * (BN / 2) + nt * 16 + ln;
        const int which = gn >> 9;  // 0=Q, 1=K (V handled above)
        const int dm = gn & 511;
        const int hh = dm >> 6, hd = dm & 63;
        const float bias = (which == 0) ? b0[dm] : b1p[dm];
        const int gm0 = m0 + wm * (BM / 2) + mt * 16 + g * 4;
        const int bq = gm0 >> 9, qq0 = gm0 & 511;
#pragma unroll
        for (int r = 0; r < 4; ++r) {
          float v = acc[mt][nt][r] + bias;
          if (which == 0) v *= 0.125f * L2E;  // fold 1/sqrt(64) and log2(e) into Q
          outH[(size_t)which * 4194304 + (((size_t)(bq * 8 + hh)) * 512 + qq0 + r) * 64 + hd] =
              (bf16)v;
        }
      } else {
#pragma unroll
        for (int r = 0; r < 4; ++r) {
          int gm = m0 + wm * (BM / 2) + mt * 16 + g * 4 + r;
          int gn = n0 + wn * (BN / 2) + nt * 16 + ln;
          float v = acc[mt][nt][r];
          if (MODE == 1) {
            v += b0[gn] + resid[(size_t)gm * 512 + gn];
            outH[(size_t)gm * 512 + gn] = (bf16)v;  // xmid in bf16
          } else if (MODE == 2) {
            v += b0[gn];
            // tanh-form GELU: v * sigmoid(2*0.7978845608*(v + 0.044715 v^3))
            float t = 2.302587f * (v + 0.044715f * v * v * v);  // 2*L2E*0.79788
            float e = __builtin_amdgcn_exp2f(t);
            v = v * e / (1.0f + e);
            outH[(size_t)gm * 2048 + gn] = (bf16)v;
          } else {
            v += b0[gn] + (float)residH[(size_t)gm * 512 + gn];
            v *= mrow[gm];
            outF[(size_t)gm * 512 + gn] = v;
          }
        }
      }
    }
  }
}

// =====================  fused attention (flash, no-max online softmax) =========
// 256 thr / 4 waves / 40KB LDS / 4 blocks/CU. K AND V^T staged via gll16.
// adj8 prefetched one tile ahead; edge bias via register cmp-select chain.
// rowlive applied only at final normalize. s_setprio on MFMA clusters.
// XCD-locality grid: blockIdx.x = h*16 + b.
__global__ __launch_bounds__(256, 4) void attn_k(
    const bf16* __restrict__ Qg, const bf16* __restrict__ Kg,
    const bf16* __restrict__ Vtg, const unsigned char* __restrict__ adj8,
    const float* __restrict__ mask, const float* __restrict__ ebias,
    bf16* __restrict__ out) {
  __shared__ __align__(16) bf16 Ksw[2][64 * 64];  // [k][d], granule ^= (k&7) via src
  __shared__ __align__(16) bf16 Vt[2][64 * 64];   // [d][k], granule ^= (d&7) via src
  __shared__ __align__(16) bf16 Pb[4][16 * 64];   // per-wave P, granule ^= (q&7)
  const int tid = threadIdx.x;
  const int l = tid & 63, w = tid >> 6, g = l >> 4, ln = l & 15;
  const int bhx = blockIdx.x;
  const int b = bhx & 15, h = bhx >> 4;
  const int bh = b * 8 + h;
  const int qt = blockIdx.y;
  const bf16* kb = Kg + (size_t)bh * 512 * 64;
  const bf16* vtb = Vtg + (size_t)bh * 64 * 512;

  int ksrc_off[2], vtsrc_off[2];
#pragma unroll
  for (int rr = 0; rr < 2; ++rr) {
    int m = w * 16 + rr * 8 + (l >> 3);
    int gs = (l & 7) ^ (l >> 3);  // (l&7)^(m&7), m&7 == l>>3
    ksrc_off[rr] = m * 64 + gs * 8;    // K row stride 64
    vtsrc_off[rr] = m * 512 + gs * 8;  // V^T row (d) stride 512
  }

  const int qrow = qt * 64 + w * 16 + ln;
  const bf16* qp = Qg + ((size_t)bh * 512 + qrow) * 64;
  bf16x8 qf0 = *(const bf16x8*)(qp + g * 8);
  bf16x8 qf1 = *(const bf16x8*)(qp + 32 + g * 8);

  const bool rowlive = mask[b * 512 + qrow] != 0.f;
  float e0 = ebias[0 * 8 + h] * L2E, e1 = ebias[1 * 8 + h] * L2E;
  float e2 = ebias[2 * 8 + h] * L2E, e3 = ebias[3 * 8 + h] * L2E;
  float e4 = ebias[4 * 8 + h] * L2E;
  const unsigned char* adjq = adj8 + ((size_t)b * 512 + qrow) * 512;

  f32x4 zero = {0.f, 0.f, 0.f, 0.f};
  f32x4 o[4];
#pragma unroll
  for (int dt = 0; dt < 4; ++dt) o[dt] = zero;
  float rsum = 0.f;
  bf16* pw = &Pb[w][0];

  // ---- prologue: stage tile 0 (K + V^T via gll16); prefetch adj bytes ----
#pragma unroll
  for (int rr = 0; rr < 2; ++rr) {
    gll16(kb + ksrc_off[rr], &Ksw[0][w * 1024 + rr * 512]);
    gll16(vtb + vtsrc_off[rr], &Vt[0][w * 1024 + rr * 512]);
  }
  uchar4 c4[4];
#pragma unroll
  for (int t4 = 0; t4 < 4; ++t4) c4[t4] = *(const uchar4*)(adjq + t4 * 16 + g * 4);
  __syncthreads();

  for (int t = 0; t < 8; ++t) {
    const int cur = t & 1, nxt = cur ^ 1;
    uchar4 n4[4];
    if (t < 7) {
      const bf16* kbt = kb + (t + 1) * 4096;
      const bf16* vbt = vtb + (t + 1) * 64;
#pragma unroll
      for (int rr = 0; rr < 2; ++rr) {
        gll16(kbt + ksrc_off[rr], &Ksw[nxt][w * 1024 + rr * 512]);
        gll16(vbt + vtsrc_off[rr], &Vt[nxt][w * 1024 + rr * 512]);
      }
#pragma unroll
      for (int t4 = 0; t4 < 4; ++t4)
        n4[t4] = *(const uchar4*)(adjq + (t + 1) * 64 + t4 * 16 + g * 4);
    }

    // ---- QK^T on current tile ----
    f32x4 s[4];
    __builtin_amdgcn_s_setprio(1);
#pragma unroll
    for (int t4 = 0; t4 < 4; ++t4) {
      int kr = t4 * 16 + ln;
      s[t4] = zero;
      bf16x8 a0 = *(const bf16x8*)&Ksw[cur][kr * 64 + ((g ^ (ln & 7)) * 8)];
      s[t4] = MFMA16(a0, qf0, s[t4], 0, 0, 0);
      bf16x8 a1 = *(const bf16x8*)&Ksw[cur][kr * 64 + (((4 + g) ^ (ln & 7)) * 8)];
      s[t4] = MFMA16(a1, qf1, s[t4], 0, 0, 0);
    }
    __builtin_amdgcn_s_setprio(0);

    // ---- edge/mask byte (register select) + exp2 (no max), rsum, stage P ----
#pragma unroll
    for (int t4 = 0; t4 < 4; ++t4) {
      unsigned char cv[4] = {c4[t4].x, c4[t4].y, c4[t4].z, c4[t4].w};
      bf16 hb[4];
#pragma unroll
      for (int r = 0; r < 4; ++r) {
        int a = cv[r] & 7;
        float eb = (a == 0) ? e0 : (a == 1) ? e1 : (a == 2) ? e2 : (a == 3) ? e3 : e4;
        float p = (cv[r] & 0x80) ? 0.f : __builtin_amdgcn_exp2f(s[t4][r] + eb);
        rsum += p;
        hb[r] = (bf16)p;
      }
      int sub = t4 * 2 + (g >> 1);
      *(uint2*)&pw[ln * 64 + ((sub ^ (ln & 7)) * 8) + (g & 1) * 4] = *(const uint2*)hb;
    }

    // ---- PV: O += P * V^T (unnormalized) ----
    __builtin_amdgcn_s_setprio(1);
#pragma unroll
    for (int ks = 0; ks < 2; ++ks) {
      bf16x8 pa = *(const bf16x8*)&pw[ln * 64 + (((ks * 4 + g) ^ (ln & 7)) * 8)];
#pragma unroll
      for (int dt = 0; dt < 4; ++dt) {
        int d = dt * 16 + ln;
        bf16x8 vvv = *(const bf16x8*)&Vt[cur][d * 64 + (((ks * 4 + g) ^ (d & 7)) * 8)];
        o[dt] = MFMA16(pa, vvv, o[dt], 0, 0, 0);
      }
    }
    __builtin_amdgcn_s_setprio(0);
    __syncthreads();
    if (t < 7) {
#pragma unroll
      for (int t4 = 0; t4 < 4; ++t4) c4[t4] = n4[t4];
    }
  }

  // ---- normalize and write (rowlive applied here: dead q-row -> 0) ----
  rsum += __shfl_xor(rsum, 16);
  rsum += __shfl_xor(rsum, 32);
  float inv = (rowlive && rsum > 0.f) ? 1.f / rsum : 0.f;
  const int qbase = qt * 64 + w * 16;
#pragma unroll
  for (int r = 0; r < 4; ++r) {
    float invr = __shfl(inv, g * 4 + r);
#pragma unroll
    for (int dt = 0; dt < 4; ++dt) {
      int q = qbase + g * 4 + r;
      out[((size_t)b * 512 + q) * 512 + h * 64 + dt * 16 + ln] = (bf16)(o[dt][r] * invr);
    }
  }
}

// ============================================================================
extern "C" void kernel_launch(void* const* d_in, const int* in_sizes, int n_in,
                              void* d_out, int out_size, void* d_ws, size_t ws_size,
                              hipStream_t stream) {
  const float* x = (const float*)d_in[0];
  const int* adj = (const int*)d_in[1];
  const float* mask = (const float*)d_in[2];
  const float* Wq = (const float*)d_in[3];
  const float* bq = (const float*)d_in[4];
  const float* Wk = (const float*)d_in[5];
  const float* bk = (const float*)d_in[6];
  const float* Wv = (const float*)d_in[7];
  const float* bv = (const float*)d_in[8];
  const float* Wo = (const float*)d_in[9];
  const float* bo = (const float*)d_in[10];
  const float* ebias = (const float*)d_in[11];
  const float* W1 = (const float*)d_in[12];
  const float* b1 = (const float*)d_in[13];
  const float* W2 = (const float*)d_in[14];
  const float* b2 = (const float*)d_in[15];
  const float* g1 = (const float*)d_in[16];
  const float* be1 = (const float*)d_in[17];
  const float* g2 = (const float*)d_in[18];
  const float* be2 = (const float*)d_in[19];
  float* outp = (float*)d_out;

  char* ws = (char*)d_ws;
  size_t off = 0;
  auto alloc = [&](size_t bytes) {
    void* p = ws + off;
    off += (bytes + 255) & ~(size_t)255;
    return p;
  };
  const size_t QSZ = 4194304;  // B*H*512*64
  bf16* h1 = (bf16*)alloc(8192UL * 512 * 2);
  bf16* wqkv = (bf16*)alloc(1536UL * 512 * 2);
  bf16* wo_t = (bf16*)alloc(512UL * 512 * 2);
  bf16* w1_t = (bf16*)alloc(2048UL * 512 * 2);
  bf16* w2_t = (bf16*)alloc(512UL * 2048 * 2);
  bf16* qkv = (bf16*)alloc(2UL * QSZ * 2);          // Q, K
  bf16* vt = (bf16*)alloc(QSZ * 2);                 // V^T [bh][d][k]
  bf16* aout = (bf16*)alloc(8192UL * 512 * 2);
  bf16* xmid = (bf16*)alloc(8192UL * 512 * 2);      // residual stream in bf16
  bf16* h2 = (bf16*)alloc(8192UL * 512 * 2);
  bf16* a1 = (bf16*)alloc(8192UL * 2048 * 2);
  unsigned char* adj8 = (unsigned char*)alloc(4194304UL);
  if (off > ws_size) return;  // workspace too small: fail cleanly

  prep_k<<<6144, 256, 0, stream>>>(adj, mask, adj8, Wq, Wk, Wv, Wo, W1, W2, wqkv,
                                   wqkv + 512 * 512, wqkv + 1024 * 512, wo_t, w1_t,
                                   w2_t, x, g1, be1, h1);
  gemm_bt<0, 128, 64><<<dim3(64, 24), 256, 0, stream>>>(
      h1, wqkv, 8192, 1536, 512, bq, bk, bv, nullptr, nullptr, nullptr, qkv, vt,
      nullptr);
  attn_k<<<dim3(128, 8), 256, 0, stream>>>(qkv, qkv + QSZ, vt, adj8, mask, ebias, aout);
  gemm_bt<1, 64, 64><<<dim3(128, 8), 256, 0, stream>>>(
      aout, wo_t, 8192, 512, 512, bo, nullptr, nullptr, x, nullptr, nullptr, xmid,
      nullptr, nullptr);
  ln_b_k<<<2048, 256, 0, stream>>>(xmid, g2, be2, h2);
  gemm_bt<2, 128, 64><<<dim3(64, 32), 256, 0, stream>>>(
      h2, w1_t, 8192, 2048, 512, b1, nullptr, nullptr, nullptr, nullptr, nullptr, a1,
      nullptr, nullptr);
  gemm_bt<3, 64, 64><<<dim3(128, 8), 256, 0, stream>>>(
      a1, w2_t, 8192, 512, 2048, b2, nullptr, nullptr, nullptr, mask, outp, nullptr,
      nullptr, xmid);
}